// Round 1
// baseline (418.800 us; speedup 1.0000x reference)
//
#include <hip/hip_runtime.h>
#include <hip/hip_bf16.h>

#define BATCH 8
#define SEQ   2048
#define FEATD 128
#define IBLK  32
#define JT    64
#define EPAD  72   // 64 + 8 bf16 pad -> 144B rows, 16B aligned, bank-balanced
#define FPAD  72

typedef __attribute__((ext_vector_type(8))) short short8;
typedef __attribute__((ext_vector_type(4))) float f32x4;

__device__ __forceinline__ unsigned short f2bf(float f) {
  unsigned int u = __float_as_uint(f);
  u += 0x7fffu + ((u >> 16) & 1u);   // round-to-nearest-even
  return (unsigned short)(u >> 16);
}

// ---------------- kernel 1: per-row stats + global max ----------------
__global__ void stats_kernel(const float* __restrict__ feature,
                             float* __restrict__ stab,
                             unsigned int* __restrict__ gmax) {
  int row  = blockIdx.x * 4 + (threadIdx.x >> 6);   // one wave per row
  int lane = threadIdx.x & 63;
  const float* rp = feature + (size_t)row * FEATD;
  float x0 = rp[lane];
  float x1 = rp[lane + 64];
  float s  = x0 + x1;
  float ss = x0 * x0 + x1 * x1;
  #pragma unroll
  for (int d = 1; d < 64; d <<= 1) {
    s  += __shfl_xor(s, d, 64);
    ss += __shfl_xor(ss, d, 64);
  }
  if (lane == 0) {
    float var = (ss - s * s * (1.0f / 128.0f)) * (1.0f / 127.0f);  // ddof=1
    float st  = 1.0f / (var + 1e-6f);
    stab[row] = st;
    atomicMax(gmax, __float_as_uint(st));  // positive floats: uint order == float order
  }
}

// ---------------- kernel 2: feature [b][j][f] f32 -> featT [b][f][j] bf16 ----------------
__global__ void transpose_kernel(const float* __restrict__ feature,
                                 unsigned short* __restrict__ featT) {
  __shared__ float tile[64][65];
  int bid = blockIdx.x;
  int b   = bid >> 6;
  int rem = bid & 63;
  int j0  = (rem >> 1) * 64;
  int f0  = (rem & 1) * 64;
  int t   = threadIdx.x;
  int tx  = t & 15, ty = t >> 4;
  const float* src = feature + ((size_t)b * SEQ + j0) * FEATD + f0;
  #pragma unroll
  for (int k = 0; k < 4; k++) {
    int j = ty + k * 16;
    float4 v = *(const float4*)(src + (size_t)j * FEATD + tx * 4);
    tile[j][tx * 4 + 0] = v.x; tile[j][tx * 4 + 1] = v.y;
    tile[j][tx * 4 + 2] = v.z; tile[j][tx * 4 + 3] = v.w;
  }
  __syncthreads();
  unsigned short* dst = featT + ((size_t)b * FEATD + f0) * SEQ + j0;
  #pragma unroll
  for (int k = 0; k < 4; k++) {
    int f = ty + k * 16;
    ushort4 o;
    o.x = f2bf(tile[tx * 4 + 0][f]);
    o.y = f2bf(tile[tx * 4 + 1][f]);
    o.z = f2bf(tile[tx * 4 + 2][f]);
    o.w = f2bf(tile[tx * 4 + 3][f]);
    *(ushort4*)(dst + (size_t)f * SEQ + tx * 4) = o;
  }
}

// ---------------- kernel 3: fused exp + (e @ feature) + row-normalize ----------------
__global__ __launch_bounds__(256, 2)
void fused_kernel(const float* __restrict__ noise,
                  const unsigned short* __restrict__ featT,
                  const float* __restrict__ stab,
                  const unsigned int* __restrict__ gmaxp,
                  float* __restrict__ out) {
  __shared__ unsigned short e_lds[IBLK][EPAD];
  __shared__ unsigned short fT[FEATD][FPAD];
  __shared__ float snorm[IBLK];
  __shared__ float rowsum[IBLK];

  int bid = blockIdx.x;
  int b   = bid >> 6;
  int i0  = (bid & 63) * IBLK;
  int t   = threadIdx.x;

  float gmax = __uint_as_float(*gmaxp);
  if (t < IBLK) snorm[t] = stab[(size_t)b * SEQ + i0 + t] * (1.0f / gmax);
  __syncthreads();

  // e-generation mapping: 32 rows x 8 j-groups of 8
  int ei  = t >> 3;
  int ejg = t & 7;
  const float* nrow = noise + ((size_t)b * SEQ + i0 + ei) * SEQ + ejg * 8;
  float sn = snorm[ei];

  // featT staging mapping: 128 f-rows x 2 halves of 32 j
  int ff = t >> 1;
  int fh = t & 1;
  const unsigned short* frow = featT + ((size_t)b * FEATD + ff) * SEQ + fh * 32;

  // wave -> output sub-tile
  int wv   = t >> 6;
  int lane = t & 63;
  int wi   = (wv >> 1) * 16;   // i sub-block (0 or 16)
  int wf   = (wv & 1) * 64;    // f sub-block (0 or 64)
  int l15  = lane & 15;
  int lg   = lane >> 4;

  f32x4 acc[4];
  #pragma unroll
  for (int k = 0; k < 4; k++) {
    f32x4 z = {0.0f, 0.0f, 0.0f, 0.0f};
    acc[k] = z;
  }
  float psum = 0.0f;

  for (int jt = 0; jt < SEQ / JT; jt++) {
    // ---- stage e tile: exp(noise*stab) -> bf16 ----
    const float4* np_ = (const float4*)(nrow + (size_t)jt * JT);
    float4 v0 = np_[0], v1 = np_[1];
    float x[8] = {v0.x, v0.y, v0.z, v0.w, v1.x, v1.y, v1.z, v1.w};
    short8 eh;
    #pragma unroll
    for (int k = 0; k < 8; k++) {
      float e = __expf(x[k] * sn);
      unsigned short h = f2bf(e);
      eh[k] = (short)h;
      psum += __uint_as_float(((unsigned int)h) << 16);  // sum the *rounded* values
    }
    *(short8*)&e_lds[ei][ejg * 8] = eh;

    // ---- stage feature tile (bf16, f-major) ----
    const uint4* fp = (const uint4*)(frow + (size_t)jt * JT);
    uint4* fd = (uint4*)&fT[ff][fh * 32];
    #pragma unroll
    for (int k = 0; k < 4; k++) fd[k] = fp[k];

    __syncthreads();

    // ---- MFMA: D[16i x 16f] += e[16 x 32] @ feat[32 x 16] ----
    #pragma unroll
    for (int ks = 0; ks < 2; ks++) {
      short8 a = *(const short8*)&e_lds[wi + l15][ks * 32 + lg * 8];
      #pragma unroll
      for (int fc = 0; fc < 4; fc++) {
        short8 bb = *(const short8*)&fT[wf + fc * 16 + l15][ks * 32 + lg * 8];
        acc[fc] = __builtin_amdgcn_mfma_f32_16x16x32_bf16(a, bb, acc[fc], 0, 0, 0);
      }
    }
    __syncthreads();
  }

  // ---- row sums: reduce over the 8 j-group threads of each row ----
  psum += __shfl_xor(psum, 1, 64);
  psum += __shfl_xor(psum, 2, 64);
  psum += __shfl_xor(psum, 4, 64);
  if (ejg == 0) rowsum[ei] = psum;
  __syncthreads();

  // ---- epilogue: divide by rowsum, write f32 ----
  float* orow = out + ((size_t)b * SEQ + i0 + wi) * FEATD + wf;
  #pragma unroll
  for (int v = 0; v < 4; v++) {
    int r = lg * 4 + v;                 // D row = (lane>>4)*4 + reg (m89-verified)
    float rinv = 1.0f / rowsum[wi + r];
    #pragma unroll
    for (int fc = 0; fc < 4; fc++) {
      orow[(size_t)r * FEATD + fc * 16 + l15] = acc[fc][v] * rinv;
    }
  }
}

extern "C" void kernel_launch(void* const* d_in, const int* in_sizes, int n_in,
                              void* d_out, int out_size, void* d_ws, size_t ws_size,
                              hipStream_t stream) {
  const float* feature = (const float*)d_in[0];
  const float* noise   = (const float*)d_in[1];
  float* out = (float*)d_out;

  // ws layout: [0,64K) stab f32[16384]; [64K] gmax u32; [128K, 128K+4.19MB) featT bf16
  float* stab          = (float*)d_ws;
  unsigned int* gmax   = (unsigned int*)((char*)d_ws + (64 << 10));
  unsigned short* featT = (unsigned short*)((char*)d_ws + (128 << 10));

  hipMemsetAsync(gmax, 0, sizeof(unsigned int), stream);
  stats_kernel<<<dim3(BATCH * SEQ / 4), dim3(256), 0, stream>>>(feature, stab, gmax);
  transpose_kernel<<<dim3(BATCH * (SEQ / 64) * (FEATD / 64)), dim3(256), 0, stream>>>(feature, featT);
  fused_kernel<<<dim3(BATCH * SEQ / IBLK), dim3(256), 0, stream>>>(noise, featT, stab, gmax, out);
}

// Round 2
// 218.238 us; speedup vs baseline: 1.9190x; 1.9190x over previous
//
#include <hip/hip_runtime.h>
#include <hip/hip_bf16.h>

#define BATCH 8
#define SEQ   2048
#define FEATD 128
#define IBLK  32
#define JT    64
#define EPAD  72   // 64 + 8 bf16 pad -> 144B rows
#define FPAD  72

typedef __attribute__((ext_vector_type(8))) short short8;
typedef __attribute__((ext_vector_type(4))) float f32x4;

__device__ __forceinline__ unsigned short f2bf(float f) {
  unsigned int u = __float_as_uint(f);
  u += 0x7fffu + ((u >> 16) & 1u);   // round-to-nearest-even
  return (unsigned short)(u >> 16);
}

// ---------------- kernel 1: fused stats (var->stab, block-reduced max) + bf16 transpose ----------------
// grid 512: b = bid>>6, j0 = (bid&63)*32. Each block: 32 full feature rows.
__global__ __launch_bounds__(256)
void prep_kernel(const float* __restrict__ feature,
                 float* __restrict__ stab,
                 unsigned int* __restrict__ gmax,
                 unsigned short* __restrict__ featT) {
  __shared__ float tile[32][132];   // 32 rows x 128 f + 4 pad
  __shared__ float wmax[4];
  int bid = blockIdx.x;
  int b   = bid >> 6;
  int j0  = (bid & 63) * 32;
  int t   = threadIdx.x;
  int r   = t >> 3;      // row 0..31
  int seg = t & 7;       // 8 segs x 16 floats

  const float* rp = feature + ((size_t)(b * SEQ + j0 + r)) * FEATD + seg * 16;
  float s = 0.0f, ss = 0.0f;
  #pragma unroll
  for (int k = 0; k < 4; k++) {
    float4 v = ((const float4*)rp)[k];
    tile[r][seg * 16 + k * 4 + 0] = v.x;
    tile[r][seg * 16 + k * 4 + 1] = v.y;
    tile[r][seg * 16 + k * 4 + 2] = v.z;
    tile[r][seg * 16 + k * 4 + 3] = v.w;
    s  += v.x + v.y + v.z + v.w;
    ss += v.x * v.x + v.y * v.y + v.z * v.z + v.w * v.w;
  }
  // reduce across the 8 segs of this row (8 consecutive lanes)
  #pragma unroll
  for (int d = 1; d < 8; d <<= 1) {
    s  += __shfl_xor(s, d, 8);
    ss += __shfl_xor(ss, d, 8);
  }
  float st = 0.0f;
  if (seg == 0) {
    float var = (ss - s * s * (1.0f / 128.0f)) * (1.0f / 127.0f);  // ddof=1
    st = 1.0f / (var + 1e-6f);
    stab[(size_t)b * SEQ + j0 + r] = st;
  }
  // wave max (non-seg0 lanes contribute 0; stab > 0 always)
  float m = st;
  #pragma unroll
  for (int d = 1; d < 64; d <<= 1) m = fmaxf(m, __shfl_xor(m, d, 64));
  if ((t & 63) == 0) wmax[t >> 6] = m;
  __syncthreads();
  if (t == 0) {
    float mm = fmaxf(fmaxf(wmax[0], wmax[1]), fmaxf(wmax[2], wmax[3]));
    atomicMax(gmax, __float_as_uint(mm));   // positive floats: uint order == float order
  }
  // phase 2: transposed bf16 write. thread t -> f = t>>1, j-half = t&1 (16 j each)
  int f  = t >> 1;
  int jh = t & 1;
  unsigned short obuf[16];
  #pragma unroll
  for (int jj = 0; jj < 16; jj++) obuf[jj] = f2bf(tile[jh * 16 + jj][f]);
  unsigned short* dst = featT + ((size_t)(b * FEATD + f)) * SEQ + j0 + jh * 16;
  *(uint4*)(dst)     = *(const uint4*)&obuf[0];
  *(uint4*)(dst + 8) = *(const uint4*)&obuf[8];
}

// ---------------- kernel 2: fused exp + (e @ feature) + row-normalize ----------------
#define LOADN(JTV, N0, N1) { const float4* p_ = (const float4*)(nrow + (size_t)(JTV) * JT); N0 = p_[0]; N1 = p_[1]; }
#define LOADF(JTV, F0, F1, F2, F3) { const uint4* p_ = (const uint4*)(frow + (size_t)(JTV) * JT); F0 = p_[0]; F1 = p_[1]; F2 = p_[2]; F3 = p_[3]; }
#define PROC(N0, N1, SLOT) { \
    float x_[8] = {N0.x, N0.y, N0.z, N0.w, N1.x, N1.y, N1.z, N1.w}; \
    short8 eh_; \
    _Pragma("unroll") \
    for (int k_ = 0; k_ < 8; k_++) { \
      float e_ = __expf(x_[k_] * sn); \
      unsigned short h_ = f2bf(e_); \
      eh_[k_] = (short)h_; \
      psum += __uint_as_float(((unsigned int)h_) << 16); \
    } \
    *(short8*)&e_lds[SLOT][ei][ejg * 8] = eh_; }
#define STOREF(SLOT, F0, F1, F2, F3) { \
    uint4* fd_ = (uint4*)&fT[SLOT][ff][fh * 32]; \
    fd_[0] = F0; fd_[1] = F1; fd_[2] = F2; fd_[3] = F3; }
#define DOMFMA(SLOT) { \
    _Pragma("unroll") \
    for (int ks = 0; ks < 2; ks++) { \
      short8 a_ = *(const short8*)&e_lds[SLOT][wi + l15][ks * 32 + lg * 8]; \
      _Pragma("unroll") \
      for (int fc = 0; fc < 4; fc++) { \
        short8 b_ = *(const short8*)&fT[SLOT][wf + fc * 16 + l15][ks * 32 + lg * 8]; \
        acc[fc] = __builtin_amdgcn_mfma_f32_16x16x32_bf16(a_, b_, acc[fc], 0, 0, 0); \
      } \
    } }

__global__ __launch_bounds__(256, 2)
void fused_kernel(const float* __restrict__ noise,
                  const unsigned short* __restrict__ featT,
                  const float* __restrict__ stab,
                  const unsigned int* __restrict__ gmaxp,
                  float* __restrict__ out) {
  __shared__ unsigned short e_lds[2][IBLK][EPAD];
  __shared__ unsigned short fT[2][FEATD][FPAD];
  __shared__ float snorm[IBLK];
  __shared__ float rowsum[IBLK];

  int bid = blockIdx.x;
  int b   = bid >> 6;
  int i0  = (bid & 63) * IBLK;
  int t   = threadIdx.x;

  float gmaxv = __uint_as_float(*gmaxp);
  if (t < IBLK) snorm[t] = stab[(size_t)b * SEQ + i0 + t] / gmaxv;
  __syncthreads();

  // e-generation mapping: 32 rows x 8 j-groups of 8
  int ei  = t >> 3;
  int ejg = t & 7;
  const float* nrow = noise + ((size_t)b * SEQ + i0 + ei) * SEQ + ejg * 8;
  float sn = snorm[ei];

  // featT staging mapping: 128 f-rows x 2 halves of 32 j
  int ff = t >> 1;
  int fh = t & 1;
  const unsigned short* frow = featT + ((size_t)b * FEATD + ff) * SEQ + fh * 32;

  // wave -> output sub-tile
  int wv   = t >> 6;
  int lane = t & 63;
  int wi   = (wv >> 1) * 16;   // i sub-block (0 or 16)
  int wf   = (wv & 1) * 64;    // f sub-block (0 or 64)
  int l15  = lane & 15;
  int lg   = lane >> 4;

  f32x4 acc[4];
  #pragma unroll
  for (int k = 0; k < 4; k++) {
    f32x4 z = {0.0f, 0.0f, 0.0f, 0.0f};
    acc[k] = z;
  }
  float psum = 0.0f;

  // register double buffers (named -> static indexing, no scratch)
  float4 nA0, nA1, nB0, nB1;
  uint4  fA0, fA1, fA2, fA3, fB0, fB1, fB2, fB3;

  LOADN(0, nA0, nA1);
  LOADF(0, fA0, fA1, fA2, fA3);

  for (int jt = 0; jt < SEQ / JT; jt += 2) {
    // even iter: use A, LDS slot 0; prefetch B = jt+1
    LOADN(jt + 1, nB0, nB1);
    LOADF(jt + 1, fB0, fB1, fB2, fB3);
    PROC(nA0, nA1, 0);
    STOREF(0, fA0, fA1, fA2, fA3);
    __syncthreads();
    DOMFMA(0);
    // odd iter: use B, LDS slot 1; prefetch A = jt+2
    if (jt + 2 < SEQ / JT) {
      LOADN(jt + 2, nA0, nA1);
      LOADF(jt + 2, fA0, fA1, fA2, fA3);
    }
    PROC(nB0, nB1, 1);
    STOREF(1, fB0, fB1, fB2, fB3);
    __syncthreads();
    DOMFMA(1);
  }

  // row sums: reduce over the 8 j-group lanes of each row
  psum += __shfl_xor(psum, 1, 64);
  psum += __shfl_xor(psum, 2, 64);
  psum += __shfl_xor(psum, 4, 64);
  if (ejg == 0) rowsum[ei] = psum;
  __syncthreads();

  // epilogue: divide by rowsum, write f32
  float* orow = out + ((size_t)b * SEQ + i0 + wi) * FEATD + wf;
  #pragma unroll
  for (int v = 0; v < 4; v++) {
    int r = lg * 4 + v;                 // D row = (lane>>4)*4 + reg (m89-verified)
    float rinv = 1.0f / rowsum[wi + r];
    #pragma unroll
    for (int fc = 0; fc < 4; fc++) {
      orow[(size_t)r * FEATD + fc * 16 + l15] = acc[fc][v] * rinv;
    }
  }
}

extern "C" void kernel_launch(void* const* d_in, const int* in_sizes, int n_in,
                              void* d_out, int out_size, void* d_ws, size_t ws_size,
                              hipStream_t stream) {
  const float* feature = (const float*)d_in[0];
  const float* noise   = (const float*)d_in[1];
  float* out = (float*)d_out;

  // ws layout: [0,64K) stab f32[16384]; [64K] gmax u32; [128K, 128K+8.4MB) featT bf16
  float* stab           = (float*)d_ws;
  unsigned int* gmax    = (unsigned int*)((char*)d_ws + (64 << 10));
  unsigned short* featT = (unsigned short*)((char*)d_ws + (128 << 10));

  hipMemsetAsync(gmax, 0, sizeof(unsigned int), stream);
  prep_kernel<<<dim3(BATCH * SEQ / 32), dim3(256), 0, stream>>>(feature, stab, gmax, featT);
  fused_kernel<<<dim3(BATCH * SEQ / IBLK), dim3(256), 0, stream>>>(noise, featT, stab, gmax, out);
}